// Round 5
// baseline (10822.147 us; speedup 1.0000x reference)
//
#include <hip/hip_runtime.h>

// ---------------------------------------------------------------------------
// LSTM autoregressive, MI355X. Round 5 (= round 4 + compile fix).
//  - BM=64 rows/block (grid 128, 1024 threads, 16 waves): weight bytes/row /2
//  - 2-product fp16 split (A=hi+lo, B=hi only, densely packed): bytes /2 again
//  - no lo prescale -> single accumulator (acc2 eliminated)
//  - dynamic LDS 114KB via hipFuncSetAttribute
// ---------------------------------------------------------------------------

typedef _Float16 f16;
typedef _Float16 f16x4 __attribute__((ext_vector_type(4)));
typedef _Float16 f16x8 __attribute__((ext_vector_type(8)));
typedef float    f32x4 __attribute__((ext_vector_type(4)));

#define MFMA16(a,b,c) __builtin_amdgcn_mfma_f32_16x16x32_f16((a),(b),(c),0,0,0)

#define BM 64     // batch rows per block

// ws layout: fp16 B-hi fragments (halves), then fp32 region (floats)
#define HOFF_E0 0        // enc L0: KT=5, NT=32  (k: [Whh 128 | Wih 6 | pad])
#define HOFF_E1 81920    // enc L1: KT=8, NT=32  (k: [Wih 128 | Whh 128])
#define HOFF_D0 212992   // dec L0: KT=5, NT=32  (k: [Whh 128 | Wih 2 | pad])
#define HOFF_D1 294912   // dec L1: KT=8, NT=32
#define HOFF_H  425984   // head W1: KT=4, NT=8
#define H_TOTAL 442368
#define FOFF    221184   // float offset of fp32 region (= H_TOTAL/2)
#define FB_E0 0
#define FB_E1 512
#define FB_D0 1024
#define FB_D1 1536
#define FB_H1 2048
#define FB_W2 2176
#define FB_B2 2432
#define F_TOTAL 2434

#define A1S 172   // A1 row stride (halves): 86 dw/row, 22r%32 bijective over 16 rows
#define A2S 140   // A2 row stride (halves): 70 dw/row,  6r%32 bijective over 16 rows
#define O1S 133   // o1 row stride (floats): 5r%32 bijective over 32 rows

#define SMEM_BYTES 113920   // 2*(64*A1S*2) + 2*(64*A2S*2) + 64*O1S*4

__device__ __forceinline__ float fsig(float x){ return 1.0f/(1.0f+__expf(-x)); }
__device__ __forceinline__ float ftanh(float x){
  float a = fabsf(x);
  float e = __expf(-2.0f*a);
  float t = (1.0f-e)/(1.0f+e);
  return x < 0.0f ? -t : t;
}

// A fragment: row = m*16 + (lane&15); k = kc + (lane>>4)*4 + j (+16 for j>=4)
template<int STRIDE>
__device__ __forceinline__ f16x8 load_afrag(const f16* buf, int m, int kc, int lane){
  const f16* p = buf + (m*16 + (lane&15))*STRIDE + kc + ((lane>>4)<<2);
  f16x4 lo = *(const f16x4*)p;
  f16x4 hi = *(const f16x4*)(p+16);
  return __builtin_shufflevector(lo, hi, 0,1,2,3,4,5,6,7);
}

__device__ __forceinline__ void init_acc(f32x4 acc[2][4],
                                         const float* __restrict__ bias, int wn, int lane){
#pragma unroll
  for (int i=0;i<4;++i){
    float bv = bias[wn*64 + i*16 + (lane&15)];
    f32x4 b4 = {bv,bv,bv,bv};
    acc[0][i]=b4; acc[1][i]=b4;
  }
}

// gates[64 rows][512 cols] += [A1|A2] * B_hi   (2-product: A_hi*B + A_lo*B)
// wave covers rows g*32..g*32+31 (mtiles g*2, g*2+1), cols wn*64..wn*64+63.
template<int KT, int SPLIT>
__device__ __forceinline__ void gemm_gates(f32x4 acc[2][4],
    const f16x8* __restrict__ Bp,
    const f16* __restrict__ A1h, const f16* __restrict__ A1l,
    const f16* __restrict__ A2h, const f16* __restrict__ A2l,
    int wn, int g, int lane)
{
  const int nbase = wn*4;
#pragma unroll
  for (int kt=0; kt<KT; ++kt){
    f16x8 B[4];
#pragma unroll
    for (int i=0;i<4;++i) B[i] = Bp[(kt*32 + nbase + i)*64 + lane];
    f16x8 a0h,a0l,a1h,a1l;
    if (kt < SPLIT){
      int kc = kt*32;
      a0h = load_afrag<A1S>(A1h, g*2+0, kc, lane);
      a0l = load_afrag<A1S>(A1l, g*2+0, kc, lane);
      a1h = load_afrag<A1S>(A1h, g*2+1, kc, lane);
      a1l = load_afrag<A1S>(A1l, g*2+1, kc, lane);
    } else {
      int kc = (kt-SPLIT)*32;
      a0h = load_afrag<A2S>(A2h, g*2+0, kc, lane);
      a0l = load_afrag<A2S>(A2l, g*2+0, kc, lane);
      a1h = load_afrag<A2S>(A2h, g*2+1, kc, lane);
      a1l = load_afrag<A2S>(A2l, g*2+1, kc, lane);
    }
#pragma unroll
    for (int i=0;i<4;++i){
      acc[0][i] = MFMA16(a0h, B[i], acc[0][i]);
      acc[1][i] = MFMA16(a1h, B[i], acc[1][i]);
    }
#pragma unroll
    for (int i=0;i<4;++i){
      acc[0][i] = MFMA16(a0l, B[i], acc[0][i]);
      acc[1][i] = MFMA16(a1l, B[i], acc[1][i]);
    }
  }
}

// 4x4 transpose within a lane-quad
__device__ __forceinline__ void quad_transpose(float&a0,float&a1,float&a2,float&a3,int q){
  bool odd = (q & 1) != 0;
  float s0 = odd ? a0 : a1, s1 = odd ? a2 : a3;
  float r0 = __shfl_xor(s0,1), r1 = __shfl_xor(s1,1);
  float b0 = odd ? r0 : a0, b1 = odd ? a1 : r0;
  float b2 = odd ? r1 : a2, b3 = odd ? a3 : r1;
  bool hi = (q & 2) != 0;
  float u0 = hi ? b0 : b2, u1 = hi ? b1 : b3;
  float v0 = __shfl_xor(u0,2), v1 = __shfl_xor(u1,2);
  a0 = hi ? v0 : b0; a1 = hi ? v1 : b1;
  a2 = hi ? b2 : v0; a3 = hi ? b3 : v1;
}

template<int DSTRIDE>
__device__ __forceinline__ void lstm_update_m(f32x4 acc[2][4], float cr[2][4],
    f16* __restrict__ Dh, f16* __restrict__ Dl, int wn, int g, int lane)
{
  const int q = lane & 3;
  const int rsub = ((lane>>4)<<2) + q;
  const int usub = wn*16 + ((lane&15)>>2);
#pragma unroll
  for (int mt=0;mt<2;++mt)
#pragma unroll
  for (int nt=0;nt<4;++nt){
    float a0=acc[mt][nt][0], a1=acc[mt][nt][1], a2=acc[mt][nt][2], a3=acc[mt][nt][3];
    quad_transpose(a0,a1,a2,a3,q);
    float iv=fsig(a0), fv=fsig(a1), gv=ftanh(a2), ov=fsig(a3);
    float cn = fv*cr[mt][nt] + iv*gv;
    cr[mt][nt] = cn;
    float h = ov*ftanh(cn);
    f16 hh = (f16)h;
    f16 hl = (f16)(h - (float)hh);
    int off = ((g*2+mt)*16 + rsub)*DSTRIDE + usub + nt*4;
    Dh[off]=hh; Dl[off]=hl;
  }
}

__global__ void __launch_bounds__(1024, 4)
lstm_main(const float* __restrict__ hist, const float* __restrict__ ws,
          float* __restrict__ out)
{
  const f16* wh = (const f16*)ws;
  const float* wf = ws + FOFF;
  const f16x8* BE0 = (const f16x8*)(wh + HOFF_E0);
  const f16x8* BE1 = (const f16x8*)(wh + HOFF_E1);
  const f16x8* BD0 = (const f16x8*)(wh + HOFF_D0);
  const f16x8* BD1 = (const f16x8*)(wh + HOFF_D1);
  const f16x8* BH  = (const f16x8*)(wh + HOFF_H);

  extern __shared__ __align__(16) char smem_raw[];
  f16*   A1h = (f16*)smem_raw;
  f16*   A1l = A1h + 64*A1S;
  f16*   A2h = A1l + 64*A1S;
  f16*   A2l = A2h + 64*A2S;
  float* o1  = (float*)(A2l + 64*A2S);

  const int tid  = threadIdx.x;
  const int w16  = tid >> 6;
  const int g    = w16 >> 3;      // row half: 0 -> rows 0..31, 1 -> rows 32..63
  const int wn   = w16 & 7;       // n-slice: cols wn*64..wn*64+63
  const int lane = tid & 63;
  const int b0   = blockIdx.x * BM;

  for (int i = tid; i < 64*A1S; i += 1024){ A1h[i]=(f16)0.f; A1l[i]=(f16)0.f; }
  for (int i = tid; i < 64*A2S; i += 1024){ A2h[i]=(f16)0.f; A2l[i]=(f16)0.f; }
  float c0r[2][4] = {{0,0,0,0},{0,0,0,0}};
  float c1r[2][4] = {{0,0,0,0},{0,0,0,0}};
  f32x4 acc[2][4];

  const int lr = tid/6, ld = tid - (tid/6)*6;   // hist loader (tid<384)

  if (tid < 384){
    float v = __builtin_nontemporal_load(&hist[(b0+lr)*768 + ld]);
    f16 hv = (f16)v;
    A1h[lr*A1S + 128 + ld] = hv;
    A1l[lr*A1S + 128 + ld] = (f16)(v - (float)hv);
  }
  __syncthreads();

  // ------------------------- encoder: 128 steps ---------------------------
  for (int t=0; t<128; ++t){
    init_acc(acc, wf + FB_E0, wn, lane);
    gemm_gates<5,99>(acc, BE0, A1h, A1l, A2h, A2l, wn, g, lane);
    __syncthreads();
    lstm_update_m<A1S>(acc, c0r, A1h, A1l, wn, g, lane);   // h0 -> A1[0..127]
    __syncthreads();

    init_acc(acc, wf + FB_E1, wn, lane);
    gemm_gates<8,4>(acc, BE1, A1h, A1l, A2h, A2l, wn, g, lane);
    if (t < 127 && tid < 384){                 // hist(t+1): x-cols idle here
      float v = __builtin_nontemporal_load(&hist[(b0+lr)*768 + (t+1)*6 + ld]);
      f16 hv = (f16)v;
      A1h[lr*A1S + 128 + ld] = hv;
      A1l[lr*A1S + 128 + ld] = (f16)(v - (float)hv);
    }
    __syncthreads();
    lstm_update_m<A2S>(acc, c1r, A2h, A2l, wn, g, lane);   // h1 -> A2[0..127]
    __syncthreads();
  }

  // decoder seed: x = hist[:, -1, :2]; zero enc-only x cols 130..133
  if (tid < 128){
    int r = tid>>1, j = tid&1;
    float v = __builtin_nontemporal_load(&hist[(b0+r)*768 + 762 + j]);
    f16 hv = (f16)v;
    A1h[r*A1S + 128 + j] = hv;
    A1l[r*A1S + 128 + j] = (f16)(v - (float)hv);
  } else if (tid < 384){
    int idx = tid - 128;
    int r = idx>>2, cl = 130 + (idx&3);
    A1h[r*A1S + cl] = (f16)0.f;
    A1l[r*A1S + cl] = (f16)0.f;
  }
  __syncthreads();

  // ------------------------- decoder: 125 steps ---------------------------
  for (int t=0; t<125; ++t){
    init_acc(acc, wf + FB_D0, wn, lane);
    gemm_gates<5,99>(acc, BD0, A1h, A1l, A2h, A2l, wn, g, lane);
    __syncthreads();
    lstm_update_m<A1S>(acc, c0r, A1h, A1l, wn, g, lane);
    __syncthreads();

    init_acc(acc, wf + FB_D1, wn, lane);
    gemm_gates<8,4>(acc, BD1, A1h, A1l, A2h, A2l, wn, g, lane);
    __syncthreads();
    lstm_update_m<A2S>(acc, c1r, A2h, A2l, wn, g, lane);
    __syncthreads();

    // head layer 1: relu(h1 @ W1^T + b1) -> o1 (fp32 LDS)
    {
      f32x4 ha[2];
      float bv = wf[FB_H1 + wn*16 + (lane&15)];
      ha[0] = (f32x4){bv,bv,bv,bv}; ha[1] = ha[0];
#pragma unroll
      for (int kt=0;kt<4;++kt){
        f16x8 bh = BH[(kt*8 + wn)*64 + lane];
        int kc = kt*32;
        f16x8 a0h = load_afrag<A2S>(A2h, g*2+0, kc, lane);
        f16x8 a0l = load_afrag<A2S>(A2l, g*2+0, kc, lane);
        f16x8 a1h = load_afrag<A2S>(A2h, g*2+1, kc, lane);
        f16x8 a1l = load_afrag<A2S>(A2l, g*2+1, kc, lane);
        ha[0] = MFMA16(a0h, bh, ha[0]);
        ha[1] = MFMA16(a1h, bh, ha[1]);
        ha[0] = MFMA16(a0l, bh, ha[0]);
        ha[1] = MFMA16(a1l, bh, ha[1]);
      }
#pragma unroll
      for (int mt=0;mt<2;++mt)
#pragma unroll
      for (int r=0;r<4;++r){
        float v = ha[mt][r];
        v = v > 0.f ? v : 0.f;
        o1[((g*2+mt)*16 + ((lane>>4)<<2) + r)*O1S + wn*16 + (lane&15)] = v;
      }
    }
    __syncthreads();

    // head layer 2 + autoregressive feedback
    if (tid < 128){
      int r = tid>>1, j = tid&1;
      const float* op = o1 + r*O1S;
      const float* w2 = wf + FB_W2 + j;
      float s0=0.f,s1=0.f,s2=0.f,s3=0.f;
#pragma unroll
      for (int k=0;k<128;k+=4){
        s0 = fmaf(op[k],   w2[2*k],   s0);
        s1 = fmaf(op[k+1], w2[2*k+2], s1);
        s2 = fmaf(op[k+2], w2[2*k+4], s2);
        s3 = fmaf(op[k+3], w2[2*k+6], s3);
      }
      float pred = wf[FB_B2 + j] + ((s0+s1)+(s2+s3));
      __builtin_nontemporal_store(pred, &out[(b0+r)*250 + t*2 + j]);
      f16 ph = (f16)pred;
      A1h[r*A1S + 128 + j] = ph;
      A1l[r*A1S + 128 + j] = (f16)(pred - (float)ph);
    }
    __syncthreads();
  }
}

// ---------------------------------------------------------------------------
// setup: pack B-hi weights into per-lane MFMA fragment order, biases fused +
// col-remapped, W2 transposed. col = unit*4 + gate; orig row = gate*128+unit.
// k element (lane,j): k = kt*32 + (j>=4?16:0) + (lane>>4)*4 + (j&3)
// ---------------------------------------------------------------------------
__global__ void setup_kernel(
    const float* __restrict__ eWih0, const float* __restrict__ eWhh0,
    const float* __restrict__ ebih0, const float* __restrict__ ebhh0,
    const float* __restrict__ eWih1, const float* __restrict__ eWhh1,
    const float* __restrict__ ebih1, const float* __restrict__ ebhh1,
    const float* __restrict__ dWih0, const float* __restrict__ dWhh0,
    const float* __restrict__ dbih0, const float* __restrict__ dbhh0,
    const float* __restrict__ dWih1, const float* __restrict__ dWhh1,
    const float* __restrict__ dbih1, const float* __restrict__ dbhh1,
    const float* __restrict__ W1, const float* __restrict__ b1,
    const float* __restrict__ W2, const float* __restrict__ b2,
    float* __restrict__ ws)
{
  int i = blockIdx.x*256 + threadIdx.x;
  if (i < H_TOTAL){
    f16* whp = (f16*)ws;
    const float *Wa, *Wb; int ka, kb, off; bool head = false;
    if      (i < HOFF_E1){ off=HOFF_E0; Wa=eWhh0; ka=128; Wb=eWih0; kb=6; }
    else if (i < HOFF_D0){ off=HOFF_E1; Wa=eWih1; ka=128; Wb=eWhh1; kb=128; }
    else if (i < HOFF_D1){ off=HOFF_D0; Wa=dWhh0; ka=128; Wb=dWih0; kb=2; }
    else if (i < HOFF_H) { off=HOFF_D1; Wa=dWih1; ka=128; Wb=dWhh1; kb=128; }
    else                 { off=HOFF_H;  Wa=W1; ka=128; Wb=W1; kb=0; head=true; }
    int local = i - off;
    int j     = local & 7;
    int lane  = (local>>3) & 63;
    int nk    = local >> 9;
    int NTl   = head ? 8 : 32;
    int n     = nk % NTl;
    int kt    = nk / NTl;
    int col   = n*16 + (lane&15);
    int koff  = ((j>>2)<<4) + ((lane>>4)<<2) + (j&3);
    int kin   = kt*32 + koff;
    float val;
    if (head){
      val = (kin < 128) ? W1[col*128 + kin] : 0.f;
    } else {
      int orow = (col&3)*128 + (col>>2);
      val = (kin < ka) ? Wa[orow*ka + kin]
          : ((kin < ka+kb) ? Wb[orow*kb + (kin-ka)] : 0.f);
    }
    whp[i] = (f16)val;
  } else if (i < H_TOTAL + F_TOTAL){
    int f = i - H_TOTAL;
    float* wfp = ws + FOFF;
    if (f < 2048){
      int layer = f >> 9, c = f & 511;
      int orow = (c&3)*128 + (c>>2);
      const float *bi, *bh;
      if      (layer==0){ bi=ebih0; bh=ebhh0; }
      else if (layer==1){ bi=ebih1; bh=ebhh1; }
      else if (layer==2){ bi=dbih0; bh=dbhh0; }
      else              { bi=dbih1; bh=dbhh1; }
      wfp[f] = bi[orow] + bh[orow];
    } else if (f < 2176){
      wfp[f] = b1[f-2048];
    } else if (f < 2432){
      int k = (f-2176)>>1, j = (f-2176)&1;
      wfp[f] = W2[j*128 + k];
    } else {
      wfp[f] = b2[f-2432];
    }
  }
}

extern "C" void kernel_launch(void* const* d_in, const int* in_sizes, int n_in,
                              void* d_out, int out_size, void* d_ws, size_t ws_size,
                              hipStream_t stream)
{
  const float* hist = (const float*)d_in[0];
  float* ws = (float*)d_ws;

  // raise dynamic-LDS cap (host-side, not a stream op; capture-safe, idempotent)
  (void)hipFuncSetAttribute(reinterpret_cast<const void*>(lstm_main),
                            hipFuncAttributeMaxDynamicSharedMemorySize, SMEM_BYTES);

  int total = H_TOTAL + F_TOTAL;
  setup_kernel<<<(total + 255)/256, 256, 0, stream>>>(
      (const float*)d_in[1],  (const float*)d_in[2],
      (const float*)d_in[3],  (const float*)d_in[4],
      (const float*)d_in[5],  (const float*)d_in[6],
      (const float*)d_in[7],  (const float*)d_in[8],
      (const float*)d_in[9],  (const float*)d_in[10],
      (const float*)d_in[11], (const float*)d_in[12],
      (const float*)d_in[13], (const float*)d_in[14],
      (const float*)d_in[15], (const float*)d_in[16],
      (const float*)d_in[17], (const float*)d_in[18],
      (const float*)d_in[19], (const float*)d_in[20],
      ws);

  lstm_main<<<128, 1024, SMEM_BYTES, stream>>>(hist, ws, (float*)d_out);
}

// Round 6
// 4536.833 us; speedup vs baseline: 2.3854x; 2.3854x over previous
//
#include <hip/hip_runtime.h>

// ---------------------------------------------------------------------------
// LSTM autoregressive, MI355X. Round 6: REGISTER-RESIDENT WEIGHTS.
//  - grid 256 (1 block/CU), 1024 threads = 16 waves, BM=32 rows/block
//  - each wave owns 2 ntiles (32 gate cols) x all 32 rows; its weight tiles
//    live in VGPRs for the whole kernel (~224 regs/wave) -> zero per-step
//    weight fetch from L2/HBM
//  - 2-product fp16 split (A=hi+lo from LDS, B=hi in regs), same numerics
//    and same setup packing as round 5
// ---------------------------------------------------------------------------

typedef _Float16 f16;
typedef _Float16 f16x4 __attribute__((ext_vector_type(4)));
typedef _Float16 f16x8 __attribute__((ext_vector_type(8)));
typedef float    f32x4 __attribute__((ext_vector_type(4)));

#define MFMA16(a,b,c) __builtin_amdgcn_mfma_f32_16x16x32_f16((a),(b),(c),0,0,0)

#define BM 32     // batch rows per block

// ws layout: fp16 B-hi fragments (halves), then fp32 region (floats)
#define HOFF_E0 0        // enc L0: KT=5, NT=32  (k: [Whh 128 | Wih 6 | pad])
#define HOFF_E1 81920    // enc L1: KT=8, NT=32  (k: [Wih 128 | Whh 128])
#define HOFF_D0 212992   // dec L0: KT=5, NT=32  (k: [Whh 128 | Wih 2 | pad])
#define HOFF_D1 294912   // dec L1: KT=8, NT=32
#define HOFF_H  425984   // head W1: KT=4, NT=8
#define H_TOTAL 442368
#define FOFF    221184   // float offset of fp32 region (= H_TOTAL/2)
#define FB_E0 0
#define FB_E1 512
#define FB_D0 1024
#define FB_D1 1536
#define FB_H1 2048
#define FB_W2 2176
#define FB_B2 2432
#define F_TOTAL 2434

#define A1S 172   // A1 row stride (halves)
#define A2S 140   // A2 row stride (halves)
#define O1S 133   // o1 row stride (floats)

__device__ __forceinline__ float fsig(float x){ return 1.0f/(1.0f+__expf(-x)); }
__device__ __forceinline__ float ftanh(float x){
  float a = fabsf(x);
  float e = __expf(-2.0f*a);
  float t = (1.0f-e)/(1.0f+e);
  return x < 0.0f ? -t : t;
}

// A fragment: row = m*16 + (lane&15); k = kc + (lane>>4)*4 + j (+16 for j>=4)
template<int STRIDE>
__device__ __forceinline__ f16x8 load_afrag(const f16* buf, int m, int kc, int lane){
  const f16* p = buf + (m*16 + (lane&15))*STRIDE + kc + ((lane>>4)<<2);
  f16x4 lo = *(const f16x4*)p;
  f16x4 hi = *(const f16x4*)(p+16);
  return __builtin_shufflevector(lo, hi, 0,1,2,3,4,5,6,7);
}

__device__ __forceinline__ void init_acc(f32x4 acc[2][2],
                                         const float* __restrict__ bias, int wv, int lane){
#pragma unroll
  for (int i=0;i<2;++i){
    float bv = bias[wv*32 + i*16 + (lane&15)];
    f32x4 b4 = {bv,bv,bv,bv};
    acc[0][i]=b4; acc[1][i]=b4;
  }
}

// gates[32 rows][wave's 32 cols] += [A1|A2] * Wreg  (A_hi*B + A_lo*B)
template<int KT, int SPLIT>
__device__ __forceinline__ void gemm_reg(f32x4 acc[2][2],
    const f16x8 W[KT][2],
    const f16* __restrict__ A1h, const f16* __restrict__ A1l,
    const f16* __restrict__ A2h, const f16* __restrict__ A2l,
    int lane)
{
#pragma unroll
  for (int kt=0; kt<KT; ++kt){
    f16x8 a0h,a0l,a1h,a1l;
    if (kt < SPLIT){
      int kc = kt*32;
      a0h = load_afrag<A1S>(A1h, 0, kc, lane);
      a0l = load_afrag<A1S>(A1l, 0, kc, lane);
      a1h = load_afrag<A1S>(A1h, 1, kc, lane);
      a1l = load_afrag<A1S>(A1l, 1, kc, lane);
    } else {
      int kc = (kt-SPLIT)*32;
      a0h = load_afrag<A2S>(A2h, 0, kc, lane);
      a0l = load_afrag<A2S>(A2l, 0, kc, lane);
      a1h = load_afrag<A2S>(A2h, 1, kc, lane);
      a1l = load_afrag<A2S>(A2l, 1, kc, lane);
    }
#pragma unroll
    for (int i=0;i<2;++i){
      acc[0][i] = MFMA16(a0h, W[kt][i], acc[0][i]);
      acc[1][i] = MFMA16(a1h, W[kt][i], acc[1][i]);
      acc[0][i] = MFMA16(a0l, W[kt][i], acc[0][i]);
      acc[1][i] = MFMA16(a1l, W[kt][i], acc[1][i]);
    }
  }
}

// 4x4 transpose within a lane-quad
__device__ __forceinline__ void quad_transpose(float&a0,float&a1,float&a2,float&a3,int q){
  bool odd = (q & 1) != 0;
  float s0 = odd ? a0 : a1, s1 = odd ? a2 : a3;
  float r0 = __shfl_xor(s0,1), r1 = __shfl_xor(s1,1);
  float b0 = odd ? r0 : a0, b1 = odd ? a1 : r0;
  float b2 = odd ? r1 : a2, b3 = odd ? a3 : r1;
  bool hi = (q & 2) != 0;
  float u0 = hi ? b0 : b2, u1 = hi ? b1 : b3;
  float v0 = __shfl_xor(u0,2), v1 = __shfl_xor(u1,2);
  a0 = hi ? v0 : b0; a1 = hi ? v1 : b1;
  a2 = hi ? b2 : v0; a3 = hi ? b3 : v1;
}

template<int DSTRIDE>
__device__ __forceinline__ void lstm_update_m(f32x4 acc[2][2], float cr[2][2],
    f16* __restrict__ Dh, f16* __restrict__ Dl, int wv, int lane)
{
  const int q = lane & 3;
  const int rsub = ((lane>>4)<<2) + q;
#pragma unroll
  for (int mt=0;mt<2;++mt)
#pragma unroll
  for (int i=0;i<2;++i){
    float a0=acc[mt][i][0], a1=acc[mt][i][1], a2=acc[mt][i][2], a3=acc[mt][i][3];
    quad_transpose(a0,a1,a2,a3,q);
    float iv=fsig(a0), fv=fsig(a1), gv=ftanh(a2), ov=fsig(a3);
    float cn = fv*cr[mt][i] + iv*gv;
    cr[mt][i] = cn;
    float h = ov*ftanh(cn);
    f16 hh = (f16)h;
    f16 hl = (f16)(h - (float)hh);
    int usub = wv*8 + i*4 + ((lane&15)>>2);
    int off = (mt*16 + rsub)*DSTRIDE + usub;
    Dh[off]=hh; Dl[off]=hl;
  }
}

__global__ void __launch_bounds__(1024, 1)
lstm_main(const float* __restrict__ hist, const float* __restrict__ ws,
          float* __restrict__ out)
{
  const f16* wh = (const f16*)ws;
  const float* wf = ws + FOFF;
  const f16x8* BE0 = (const f16x8*)(wh + HOFF_E0);
  const f16x8* BE1 = (const f16x8*)(wh + HOFF_E1);
  const f16x8* BD0 = (const f16x8*)(wh + HOFF_D0);
  const f16x8* BD1 = (const f16x8*)(wh + HOFF_D1);
  const f16x8* BH  = (const f16x8*)(wh + HOFF_H);

  __shared__ __align__(16) f16 A1h[32*A1S], A1l[32*A1S];
  __shared__ __align__(16) f16 A2h[32*A2S], A2l[32*A2S];
  __shared__ __align__(16) float o1buf[32*O1S];

  const int tid  = threadIdx.x;
  const int wv   = tid >> 6;      // wave 0..15: gate cols [wv*32, wv*32+32)
  const int lane = tid & 63;
  const int b0   = blockIdx.x * BM;

  for (int i = tid; i < 32*A1S; i += 1024){ A1h[i]=(f16)0.f; A1l[i]=(f16)0.f; }
  for (int i = tid; i < 32*A2S; i += 1024){ A2h[i]=(f16)0.f; A2l[i]=(f16)0.f; }
  float c0r[2][2] = {{0,0},{0,0}};
  float c1r[2][2] = {{0,0},{0,0}};
  f32x4 acc[2][2];

  const int lr = tid/6, ld = tid - (tid/6)*6;   // hist loader (tid<192)

  // ---- encoder weights -> registers (one-time) ----
  f16x8 WE0[5][2], WE1[8][2];
#pragma unroll
  for (int kt=0;kt<5;++kt)
#pragma unroll
    for (int i=0;i<2;++i) WE0[kt][i] = BE0[(kt*32 + wv*2 + i)*64 + lane];
#pragma unroll
  for (int kt=0;kt<8;++kt)
#pragma unroll
    for (int i=0;i<2;++i) WE1[kt][i] = BE1[(kt*32 + wv*2 + i)*64 + lane];

  if (tid < 192){
    float v = hist[(b0+lr)*768 + ld];
    f16 hv = (f16)v;
    A1h[lr*A1S + 128 + ld] = hv;
    A1l[lr*A1S + 128 + ld] = (f16)(v - (float)hv);
  }
  __syncthreads();

  // ------------------------- encoder: 128 steps ---------------------------
  for (int t=0; t<128; ++t){
    init_acc(acc, wf + FB_E0, wv, lane);
    gemm_reg<5,99>(acc, WE0, A1h, A1l, A2h, A2l, lane);
    __syncthreads();
    lstm_update_m<A1S>(acc, c0r, A1h, A1l, wv, lane);   // h0 -> A1[0..127]
    __syncthreads();

    init_acc(acc, wf + FB_E1, wv, lane);
    gemm_reg<8,4>(acc, WE1, A1h, A1l, A2h, A2l, lane);
    if (t < 127 && tid < 192){                 // hist(t+1): x-cols idle here
      float v = hist[(b0+lr)*768 + (t+1)*6 + ld];
      f16 hv = (f16)v;
      A1h[lr*A1S + 128 + ld] = hv;
      A1l[lr*A1S + 128 + ld] = (f16)(v - (float)hv);
    }
    __syncthreads();
    lstm_update_m<A2S>(acc, c1r, A2h, A2l, wv, lane);   // h1 -> A2[0..127]
    __syncthreads();
  }

  // ---- decoder + head weights -> registers (encoder weights now dead) ----
  f16x8 WD0[5][2], WD1[8][2], WH[4];
#pragma unroll
  for (int kt=0;kt<5;++kt)
#pragma unroll
    for (int i=0;i<2;++i) WD0[kt][i] = BD0[(kt*32 + wv*2 + i)*64 + lane];
#pragma unroll
  for (int kt=0;kt<8;++kt)
#pragma unroll
    for (int i=0;i<2;++i) WD1[kt][i] = BD1[(kt*32 + wv*2 + i)*64 + lane];
  {
    const int nh = wv & 7;
#pragma unroll
    for (int kt=0;kt<4;++kt) WH[kt] = BH[(kt*8 + nh)*64 + lane];
  }

  // decoder seed: x = hist[:, -1, :2]; zero enc-only x cols 130..133
  if (tid < 64){
    int r = tid>>1, j = tid&1;
    float v = hist[(b0+r)*768 + 762 + j];
    f16 hv = (f16)v;
    A1h[r*A1S + 128 + j] = hv;
    A1l[r*A1S + 128 + j] = (f16)(v - (float)hv);
  } else if (tid < 192){
    int idx = tid - 64;
    int r = idx>>2, cl = 130 + (idx&3);
    A1h[r*A1S + cl] = (f16)0.f;
    A1l[r*A1S + cl] = (f16)0.f;
  }
  __syncthreads();

  // ------------------------- decoder: 125 steps ---------------------------
  for (int t=0; t<125; ++t){
    init_acc(acc, wf + FB_D0, wv, lane);
    gemm_reg<5,99>(acc, WD0, A1h, A1l, A2h, A2l, lane);
    __syncthreads();
    lstm_update_m<A1S>(acc, c0r, A1h, A1l, wv, lane);
    __syncthreads();

    init_acc(acc, wf + FB_D1, wv, lane);
    gemm_reg<8,4>(acc, WD1, A1h, A1l, A2h, A2l, lane);
    __syncthreads();
    lstm_update_m<A2S>(acc, c1r, A2h, A2l, wv, lane);
    __syncthreads();

    // head layer 1: relu(h1 @ W1^T + b1) -> o1 (fp32 LDS)
    {
      const int mt_h = wv >> 3;       // waves 0-7: rows 0..15; waves 8-15: rows 16..31
      const int nh   = wv & 7;        // 16 output cols each
      float bv = wf[FB_H1 + nh*16 + (lane&15)];
      f32x4 ha = {bv,bv,bv,bv};
#pragma unroll
      for (int kt=0;kt<4;++kt){
        int kc = kt*32;
        f16x8 ah = load_afrag<A2S>(A2h, mt_h, kc, lane);
        f16x8 al = load_afrag<A2S>(A2l, mt_h, kc, lane);
        ha = MFMA16(ah, WH[kt], ha);
        ha = MFMA16(al, WH[kt], ha);
      }
#pragma unroll
      for (int r=0;r<4;++r){
        float v = ha[r];
        v = v > 0.f ? v : 0.f;
        o1buf[(mt_h*16 + ((lane>>4)<<2) + r)*O1S + nh*16 + (lane&15)] = v;
      }
    }
    __syncthreads();

    // head layer 2 + autoregressive feedback
    if (tid < 64){
      int r = tid>>1, j = tid&1;
      const float* op = o1buf + r*O1S;
      const float* w2 = wf + FB_W2 + j;
      float s0=0.f,s1=0.f,s2=0.f,s3=0.f;
#pragma unroll
      for (int k=0;k<128;k+=4){
        s0 = fmaf(op[k],   w2[2*k],   s0);
        s1 = fmaf(op[k+1], w2[2*k+2], s1);
        s2 = fmaf(op[k+2], w2[2*k+4], s2);
        s3 = fmaf(op[k+3], w2[2*k+6], s3);
      }
      float pred = wf[FB_B2 + j] + ((s0+s1)+(s2+s3));
      out[(b0+r)*250 + t*2 + j] = pred;
      f16 ph = (f16)pred;
      A1h[r*A1S + 128 + j] = ph;
      A1l[r*A1S + 128 + j] = (f16)(pred - (float)ph);
    }
    __syncthreads();
  }
}

// ---------------------------------------------------------------------------
// setup: pack B-hi weights into per-lane MFMA fragment order, biases fused +
// col-remapped, W2 transposed. col = unit*4 + gate; orig row = gate*128+unit.
// k element (lane,j): k = kt*32 + (j>=4?16:0) + (lane>>4)*4 + (j&3)
// (identical to round 5)
// ---------------------------------------------------------------------------
__global__ void setup_kernel(
    const float* __restrict__ eWih0, const float* __restrict__ eWhh0,
    const float* __restrict__ ebih0, const float* __restrict__ ebhh0,
    const float* __restrict__ eWih1, const float* __restrict__ eWhh1,
    const float* __restrict__ ebih1, const float* __restrict__ ebhh1,
    const float* __restrict__ dWih0, const float* __restrict__ dWhh0,
    const float* __restrict__ dbih0, const float* __restrict__ dbhh0,
    const float* __restrict__ dWih1, const float* __restrict__ dWhh1,
    const float* __restrict__ dbih1, const float* __restrict__ dbhh1,
    const float* __restrict__ W1, const float* __restrict__ b1,
    const float* __restrict__ W2, const float* __restrict__ b2,
    float* __restrict__ ws)
{
  int i = blockIdx.x*256 + threadIdx.x;
  if (i < H_TOTAL){
    f16* whp = (f16*)ws;
    const float *Wa, *Wb; int ka, kb, off; bool head = false;
    if      (i < HOFF_E1){ off=HOFF_E0; Wa=eWhh0; ka=128; Wb=eWih0; kb=6; }
    else if (i < HOFF_D0){ off=HOFF_E1; Wa=eWih1; ka=128; Wb=eWhh1; kb=128; }
    else if (i < HOFF_D1){ off=HOFF_D0; Wa=dWhh0; ka=128; Wb=dWih0; kb=2; }
    else if (i < HOFF_H) { off=HOFF_D1; Wa=dWih1; ka=128; Wb=dWhh1; kb=128; }
    else                 { off=HOFF_H;  Wa=W1; ka=128; Wb=W1; kb=0; head=true; }
    int local = i - off;
    int j     = local & 7;
    int lane  = (local>>3) & 63;
    int nk    = local >> 9;
    int NTl   = head ? 8 : 32;
    int n     = nk % NTl;
    int kt    = nk / NTl;
    int col   = n*16 + (lane&15);
    int koff  = ((j>>2)<<4) + ((lane>>4)<<2) + (j&3);
    int kin   = kt*32 + koff;
    float val;
    if (head){
      val = (kin < 128) ? W1[col*128 + kin] : 0.f;
    } else {
      int orow = (col&3)*128 + (col>>2);
      val = (kin < ka) ? Wa[orow*ka + kin]
          : ((kin < ka+kb) ? Wb[orow*kb + (kin-ka)] : 0.f);
    }
    whp[i] = (f16)val;
  } else if (i < H_TOTAL + F_TOTAL){
    int f = i - H_TOTAL;
    float* wfp = ws + FOFF;
    if (f < 2048){
      int layer = f >> 9, c = f & 511;
      int orow = (c&3)*128 + (c>>2);
      const float *bi, *bh;
      if      (layer==0){ bi=ebih0; bh=ebhh0; }
      else if (layer==1){ bi=ebih1; bh=ebhh1; }
      else if (layer==2){ bi=dbih0; bh=dbhh0; }
      else              { bi=dbih1; bh=dbhh1; }
      wfp[f] = bi[orow] + bh[orow];
    } else if (f < 2176){
      wfp[f] = b1[f-2048];
    } else if (f < 2432){
      int k = (f-2176)>>1, j = (f-2176)&1;
      wfp[f] = W2[j*128 + k];
    } else {
      wfp[f] = b2[f-2432];
    }
  }
}

extern "C" void kernel_launch(void* const* d_in, const int* in_sizes, int n_in,
                              void* d_out, int out_size, void* d_ws, size_t ws_size,
                              hipStream_t stream)
{
  const float* hist = (const float*)d_in[0];
  float* ws = (float*)d_ws;

  int total = H_TOTAL + F_TOTAL;
  setup_kernel<<<(total + 255)/256, 256, 0, stream>>>(
      (const float*)d_in[1],  (const float*)d_in[2],
      (const float*)d_in[3],  (const float*)d_in[4],
      (const float*)d_in[5],  (const float*)d_in[6],
      (const float*)d_in[7],  (const float*)d_in[8],
      (const float*)d_in[9],  (const float*)d_in[10],
      (const float*)d_in[11], (const float*)d_in[12],
      (const float*)d_in[13], (const float*)d_in[14],
      (const float*)d_in[15], (const float*)d_in[16],
      (const float*)d_in[17], (const float*)d_in[18],
      (const float*)d_in[19], (const float*)d_in[20],
      ws);

  lstm_main<<<256, 1024, 0, stream>>>(hist, ws, (float*)d_out);
}

// Round 7
// 4500.309 us; speedup vs baseline: 2.4048x; 1.0081x over previous
//
#include <hip/hip_runtime.h>

// ---------------------------------------------------------------------------
// LSTM autoregressive, MI355X. Round 7: register-resident weights, FORCED.
//  - grid 256 (1 block/CU), 1024 threads = 16 waves (4/SIMD -> 512 VGPR cap)
//  - each wave owns 32 gate cols; weight fragments pinned in VGPRs via
//    opaque inline-asm (prevents compiler rematerialization that caused
//    round 6's 10 GB/step re-fetch, VGPR_Count=64)
//  - biases also register-pinned: zero loop-invariant global loads in loop
//  - 2-product fp16 split (A=hi+lo from LDS, B=hi in regs), numerics as r6
// ---------------------------------------------------------------------------

typedef _Float16 f16;
typedef _Float16 f16x4 __attribute__((ext_vector_type(4)));
typedef _Float16 f16x8 __attribute__((ext_vector_type(8)));
typedef float    f32x4 __attribute__((ext_vector_type(4)));

#define MFMA16(a,b,c) __builtin_amdgcn_mfma_f32_16x16x32_f16((a),(b),(c),0,0,0)

// pin a value in VGPRs: asm result cannot be rematerialized by the compiler
#define KEEP(x) asm("" : "+v"(x))

#define BM 32     // batch rows per block

// ws layout: fp16 B-hi fragments (halves), then fp32 region (floats)
#define HOFF_E0 0        // enc L0: KT=5, NT=32  (k: [Whh 128 | Wih 6 | pad])
#define HOFF_E1 81920    // enc L1: KT=8, NT=32  (k: [Wih 128 | Whh 128])
#define HOFF_D0 212992   // dec L0: KT=5, NT=32  (k: [Whh 128 | Wih 2 | pad])
#define HOFF_D1 294912   // dec L1: KT=8, NT=32
#define HOFF_H  425984   // head W1: KT=4, NT=8
#define H_TOTAL 442368
#define FOFF    221184   // float offset of fp32 region (= H_TOTAL/2)
#define FB_E0 0
#define FB_E1 512
#define FB_D0 1024
#define FB_D1 1536
#define FB_H1 2048
#define FB_W2 2176
#define FB_B2 2432
#define F_TOTAL 2434

#define A1S 172   // A1 row stride (halves)
#define A2S 140   // A2 row stride (halves)
#define O1S 133   // o1 row stride (floats)

__device__ __forceinline__ float fsig(float x){ return 1.0f/(1.0f+__expf(-x)); }
__device__ __forceinline__ float ftanh(float x){
  float a = fabsf(x);
  float e = __expf(-2.0f*a);
  float t = (1.0f-e)/(1.0f+e);
  return x < 0.0f ? -t : t;
}

// A fragment: row = m*16 + (lane&15); k = kc + (lane>>4)*4 + j (+16 for j>=4)
template<int STRIDE>
__device__ __forceinline__ f16x8 load_afrag(const f16* buf, int m, int kc, int lane){
  const f16* p = buf + (m*16 + (lane&15))*STRIDE + kc + ((lane>>4)<<2);
  f16x4 lo = *(const f16x4*)p;
  f16x4 hi = *(const f16x4*)(p+16);
  return __builtin_shufflevector(lo, hi, 0,1,2,3,4,5,6,7);
}

__device__ __forceinline__ void init_acc(f32x4 acc[2][2], float b0v, float b1v){
  f32x4 b4a = {b0v,b0v,b0v,b0v};
  f32x4 b4b = {b1v,b1v,b1v,b1v};
  acc[0][0]=b4a; acc[1][0]=b4a;
  acc[0][1]=b4b; acc[1][1]=b4b;
}

// gates[32 rows][wave's 32 cols] += [A1|A2] * Wreg  (A_hi*B + A_lo*B)
template<int KT, int SPLIT>
__device__ __forceinline__ void gemm_reg(f32x4 acc[2][2],
    const f16x8 W[KT][2],
    const f16* __restrict__ A1h, const f16* __restrict__ A1l,
    const f16* __restrict__ A2h, const f16* __restrict__ A2l,
    int lane)
{
#pragma unroll
  for (int kt=0; kt<KT; ++kt){
    f16x8 a0h,a0l,a1h,a1l;
    if (kt < SPLIT){
      int kc = kt*32;
      a0h = load_afrag<A1S>(A1h, 0, kc, lane);
      a0l = load_afrag<A1S>(A1l, 0, kc, lane);
      a1h = load_afrag<A1S>(A1h, 1, kc, lane);
      a1l = load_afrag<A1S>(A1l, 1, kc, lane);
    } else {
      int kc = (kt-SPLIT)*32;
      a0h = load_afrag<A2S>(A2h, 0, kc, lane);
      a0l = load_afrag<A2S>(A2l, 0, kc, lane);
      a1h = load_afrag<A2S>(A2h, 1, kc, lane);
      a1l = load_afrag<A2S>(A2l, 1, kc, lane);
    }
#pragma unroll
    for (int i=0;i<2;++i){
      acc[0][i] = MFMA16(a0h, W[kt][i], acc[0][i]);
      acc[1][i] = MFMA16(a1h, W[kt][i], acc[1][i]);
      acc[0][i] = MFMA16(a0l, W[kt][i], acc[0][i]);
      acc[1][i] = MFMA16(a1l, W[kt][i], acc[1][i]);
    }
  }
}

// 4x4 transpose within a lane-quad
__device__ __forceinline__ void quad_transpose(float&a0,float&a1,float&a2,float&a3,int q){
  bool odd = (q & 1) != 0;
  float s0 = odd ? a0 : a1, s1 = odd ? a2 : a3;
  float r0 = __shfl_xor(s0,1), r1 = __shfl_xor(s1,1);
  float b0 = odd ? r0 : a0, b1 = odd ? a1 : r0;
  float b2 = odd ? r1 : a2, b3 = odd ? a3 : r1;
  bool hi = (q & 2) != 0;
  float u0 = hi ? b0 : b2, u1 = hi ? b1 : b3;
  float v0 = __shfl_xor(u0,2), v1 = __shfl_xor(u1,2);
  a0 = hi ? v0 : b0; a1 = hi ? v1 : b1;
  a2 = hi ? b2 : v0; a3 = hi ? b3 : v1;
}

template<int DSTRIDE>
__device__ __forceinline__ void lstm_update_m(f32x4 acc[2][2], float cr[2][2],
    f16* __restrict__ Dh, f16* __restrict__ Dl, int wv, int lane)
{
  const int q = lane & 3;
  const int rsub = ((lane>>4)<<2) + q;
#pragma unroll
  for (int mt=0;mt<2;++mt)
#pragma unroll
  for (int i=0;i<2;++i){
    float a0=acc[mt][i][0], a1=acc[mt][i][1], a2=acc[mt][i][2], a3=acc[mt][i][3];
    quad_transpose(a0,a1,a2,a3,q);
    float iv=fsig(a0), fv=fsig(a1), gv=ftanh(a2), ov=fsig(a3);
    float cn = fv*cr[mt][i] + iv*gv;
    cr[mt][i] = cn;
    float h = ov*ftanh(cn);
    f16 hh = (f16)h;
    f16 hl = (f16)(h - (float)hh);
    int usub = wv*8 + i*4 + ((lane&15)>>2);
    int off = (mt*16 + rsub)*DSTRIDE + usub;
    Dh[off]=hh; Dl[off]=hl;
  }
}

__global__ void __launch_bounds__(1024, 4)
lstm_main(const float* __restrict__ hist, const float* __restrict__ ws,
          float* __restrict__ out)
{
  const f16* wh = (const f16*)ws;
  const float* wf = ws + FOFF;
  const f16x8* BE0 = (const f16x8*)(wh + HOFF_E0);
  const f16x8* BE1 = (const f16x8*)(wh + HOFF_E1);
  const f16x8* BD0 = (const f16x8*)(wh + HOFF_D0);
  const f16x8* BD1 = (const f16x8*)(wh + HOFF_D1);
  const f16x8* BH  = (const f16x8*)(wh + HOFF_H);

  __shared__ __align__(16) f16 A1h[32*A1S], A1l[32*A1S];
  __shared__ __align__(16) f16 A2h[32*A2S], A2l[32*A2S];
  __shared__ __align__(16) float o1buf[32*O1S];

  const int tid  = threadIdx.x;
  const int wv   = tid >> 6;      // wave 0..15: gate cols [wv*32, wv*32+32)
  const int lane = tid & 63;
  const int b0   = blockIdx.x * BM;

  for (int i = tid; i < 32*A1S; i += 1024){ A1h[i]=(f16)0.f; A1l[i]=(f16)0.f; }
  for (int i = tid; i < 32*A2S; i += 1024){ A2h[i]=(f16)0.f; A2l[i]=(f16)0.f; }
  float c0r[2][2] = {{0,0},{0,0}};
  float c1r[2][2] = {{0,0},{0,0}};
  f32x4 acc[2][2];

  const int lr = tid/6, ld = tid - (tid/6)*6;   // hist loader (tid<192)
  const int lidx = lane & 15;

  // ---- encoder weights + biases -> registers, PINNED ----
  f16x8 WE0[5][2], WE1[8][2];
#pragma unroll
  for (int kt=0;kt<5;++kt)
#pragma unroll
    for (int i=0;i<2;++i){ WE0[kt][i] = BE0[(kt*32 + wv*2 + i)*64 + lane]; KEEP(WE0[kt][i]); }
#pragma unroll
  for (int kt=0;kt<8;++kt)
#pragma unroll
    for (int i=0;i<2;++i){ WE1[kt][i] = BE1[(kt*32 + wv*2 + i)*64 + lane]; KEEP(WE1[kt][i]); }

  float bE0a = wf[FB_E0 + wv*32 + lidx],      bE0b = wf[FB_E0 + wv*32 + 16 + lidx];
  float bE1a = wf[FB_E1 + wv*32 + lidx],      bE1b = wf[FB_E1 + wv*32 + 16 + lidx];
  KEEP(bE0a); KEEP(bE0b); KEEP(bE1a); KEEP(bE1b);

  if (tid < 192){
    float v = hist[(b0+lr)*768 + ld];
    f16 hv = (f16)v;
    A1h[lr*A1S + 128 + ld] = hv;
    A1l[lr*A1S + 128 + ld] = (f16)(v - (float)hv);
  }
  __syncthreads();

  // ------------------------- encoder: 128 steps ---------------------------
  for (int t=0; t<128; ++t){
    init_acc(acc, bE0a, bE0b);
    gemm_reg<5,99>(acc, WE0, A1h, A1l, A2h, A2l, lane);
    __syncthreads();
    lstm_update_m<A1S>(acc, c0r, A1h, A1l, wv, lane);   // h0 -> A1[0..127]
    __syncthreads();

    init_acc(acc, bE1a, bE1b);
    gemm_reg<8,4>(acc, WE1, A1h, A1l, A2h, A2l, lane);
    if (t < 127 && tid < 192){                 // hist(t+1): x-cols idle here
      float v = hist[(b0+lr)*768 + (t+1)*6 + ld];
      f16 hv = (f16)v;
      A1h[lr*A1S + 128 + ld] = hv;
      A1l[lr*A1S + 128 + ld] = (f16)(v - (float)hv);
    }
    __syncthreads();
    lstm_update_m<A2S>(acc, c1r, A2h, A2l, wv, lane);   // h1 -> A2[0..127]
    __syncthreads();
  }

  // ---- decoder + head weights -> registers, PINNED (enc weights dead) ----
  f16x8 WD0[5][2], WD1[8][2], WH[4];
#pragma unroll
  for (int kt=0;kt<5;++kt)
#pragma unroll
    for (int i=0;i<2;++i){ WD0[kt][i] = BD0[(kt*32 + wv*2 + i)*64 + lane]; KEEP(WD0[kt][i]); }
#pragma unroll
  for (int kt=0;kt<8;++kt)
#pragma unroll
    for (int i=0;i<2;++i){ WD1[kt][i] = BD1[(kt*32 + wv*2 + i)*64 + lane]; KEEP(WD1[kt][i]); }
  {
    const int nh = wv & 7;
#pragma unroll
    for (int kt=0;kt<4;++kt){ WH[kt] = BH[(kt*8 + nh)*64 + lane]; KEEP(WH[kt]); }
  }
  float bD0a = wf[FB_D0 + wv*32 + lidx],      bD0b = wf[FB_D0 + wv*32 + 16 + lidx];
  float bD1a = wf[FB_D1 + wv*32 + lidx],      bD1b = wf[FB_D1 + wv*32 + 16 + lidx];
  float bH1  = wf[FB_H1 + (wv&7)*16 + lidx];
  KEEP(bD0a); KEEP(bD0b); KEEP(bD1a); KEEP(bD1b); KEEP(bH1);

  // decoder seed: x = hist[:, -1, :2]; zero enc-only x cols 130..133
  if (tid < 64){
    int r = tid>>1, j = tid&1;
    float v = hist[(b0+r)*768 + 762 + j];
    f16 hv = (f16)v;
    A1h[r*A1S + 128 + j] = hv;
    A1l[r*A1S + 128 + j] = (f16)(v - (float)hv);
  } else if (tid < 192){
    int idx = tid - 64;
    int r = idx>>2, cl = 130 + (idx&3);
    A1h[r*A1S + cl] = (f16)0.f;
    A1l[r*A1S + cl] = (f16)0.f;
  }
  __syncthreads();

  // ------------------------- decoder: 125 steps ---------------------------
  for (int t=0; t<125; ++t){
    init_acc(acc, bD0a, bD0b);
    gemm_reg<5,99>(acc, WD0, A1h, A1l, A2h, A2l, lane);
    __syncthreads();
    lstm_update_m<A1S>(acc, c0r, A1h, A1l, wv, lane);
    __syncthreads();

    init_acc(acc, bD1a, bD1b);
    gemm_reg<8,4>(acc, WD1, A1h, A1l, A2h, A2l, lane);
    __syncthreads();
    lstm_update_m<A2S>(acc, c1r, A2h, A2l, wv, lane);
    __syncthreads();

    // head layer 1: relu(h1 @ W1^T + b1) -> o1 (fp32 LDS)
    {
      const int mt_h = wv >> 3;       // waves 0-7: rows 0..15; waves 8-15: rows 16..31
      const int nh   = wv & 7;        // 16 output cols each
      f32x4 ha = {bH1,bH1,bH1,bH1};
#pragma unroll
      for (int kt=0;kt<4;++kt){
        int kc = kt*32;
        f16x8 ah = load_afrag<A2S>(A2h, mt_h, kc, lane);
        f16x8 al = load_afrag<A2S>(A2l, mt_h, kc, lane);
        ha = MFMA16(ah, WH[kt], ha);
        ha = MFMA16(al, WH[kt], ha);
      }
#pragma unroll
      for (int r=0;r<4;++r){
        float v = ha[r];
        v = v > 0.f ? v : 0.f;
        o1buf[(mt_h*16 + ((lane>>4)<<2) + r)*O1S + nh*16 + lidx] = v;
      }
    }
    __syncthreads();

    // head layer 2 + autoregressive feedback
    if (tid < 64){
      int r = tid>>1, j = tid&1;
      const float* op = o1buf + r*O1S;
      const float* w2 = wf + FB_W2 + j;
      float s0=0.f,s1=0.f,s2=0.f,s3=0.f;
#pragma unroll
      for (int k=0;k<128;k+=4){
        s0 = fmaf(op[k],   w2[2*k],   s0);
        s1 = fmaf(op[k+1], w2[2*k+2], s1);
        s2 = fmaf(op[k+2], w2[2*k+4], s2);
        s3 = fmaf(op[k+3], w2[2*k+6], s3);
      }
      float pred = wf[FB_B2 + j] + ((s0+s1)+(s2+s3));
      out[(b0+r)*250 + t*2 + j] = pred;
      f16 ph = (f16)pred;
      A1h[r*A1S + 128 + j] = ph;
      A1l[r*A1S + 128 + j] = (f16)(pred - (float)ph);
    }
    __syncthreads();
  }
}

// ---------------------------------------------------------------------------
// setup: pack B-hi weights into per-lane MFMA fragment order, biases fused +
// col-remapped, W2 transposed. col = unit*4 + gate; orig row = gate*128+unit.
// k element (lane,j): k = kt*32 + (j>=4?16:0) + (lane>>4)*4 + (j&3)
// (identical to rounds 5/6)
// ---------------------------------------------------------------------------
__global__ void setup_kernel(
    const float* __restrict__ eWih0, const float* __restrict__ eWhh0,
    const float* __restrict__ ebih0, const float* __restrict__ ebhh0,
    const float* __restrict__ eWih1, const float* __restrict__ eWhh1,
    const float* __restrict__ ebih1, const float* __restrict__ ebhh1,
    const float* __restrict__ dWih0, const float* __restrict__ dWhh0,
    const float* __restrict__ dbih0, const float* __restrict__ dbhh0,
    const float* __restrict__ dWih1, const float* __restrict__ dWhh1,
    const float* __restrict__ dbih1, const float* __restrict__ dbhh1,
    const float* __restrict__ W1, const float* __restrict__ b1,
    const float* __restrict__ W2, const float* __restrict__ b2,
    float* __restrict__ ws)
{
  int i = blockIdx.x*256 + threadIdx.x;
  if (i < H_TOTAL){
    f16* whp = (f16*)ws;
    const float *Wa, *Wb; int ka, kb, off; bool head = false;
    if      (i < HOFF_E1){ off=HOFF_E0; Wa=eWhh0; ka=128; Wb=eWih0; kb=6; }
    else if (i < HOFF_D0){ off=HOFF_E1; Wa=eWih1; ka=128; Wb=eWhh1; kb=128; }
    else if (i < HOFF_D1){ off=HOFF_D0; Wa=dWhh0; ka=128; Wb=dWih0; kb=2; }
    else if (i < HOFF_H) { off=HOFF_D1; Wa=dWih1; ka=128; Wb=dWhh1; kb=128; }
    else                 { off=HOFF_H;  Wa=W1; ka=128; Wb=W1; kb=0; head=true; }
    int local = i - off;
    int j     = local & 7;
    int lane  = (local>>3) & 63;
    int nk    = local >> 9;
    int NTl   = head ? 8 : 32;
    int n     = nk % NTl;
    int kt    = nk / NTl;
    int col   = n*16 + (lane&15);
    int koff  = ((j>>2)<<4) + ((lane>>4)<<2) + (j&3);
    int kin   = kt*32 + koff;
    float val;
    if (head){
      val = (kin < 128) ? W1[col*128 + kin] : 0.f;
    } else {
      int orow = (col&3)*128 + (col>>2);
      val = (kin < ka) ? Wa[orow*ka + kin]
          : ((kin < ka+kb) ? Wb[orow*kb + (kin-ka)] : 0.f);
    }
    whp[i] = (f16)val;
  } else if (i < H_TOTAL + F_TOTAL){
    int f = i - H_TOTAL;
    float* wfp = ws + FOFF;
    if (f < 2048){
      int layer = f >> 9, c = f & 511;
      int orow = (c&3)*128 + (c>>2);
      const float *bi, *bh;
      if      (layer==0){ bi=ebih0; bh=ebhh0; }
      else if (layer==1){ bi=ebih1; bh=ebhh1; }
      else if (layer==2){ bi=dbih0; bh=dbhh0; }
      else              { bi=dbih1; bh=dbhh1; }
      wfp[f] = bi[orow] + bh[orow];
    } else if (f < 2176){
      wfp[f] = b1[f-2048];
    } else if (f < 2432){
      int k = (f-2176)>>1, j = (f-2176)&1;
      wfp[f] = W2[j*128 + k];
    } else {
      wfp[f] = b2[f-2432];
    }
  }
}

extern "C" void kernel_launch(void* const* d_in, const int* in_sizes, int n_in,
                              void* d_out, int out_size, void* d_ws, size_t ws_size,
                              hipStream_t stream)
{
  const float* hist = (const float*)d_in[0];
  float* ws = (float*)d_ws;

  int total = H_TOTAL + F_TOTAL;
  setup_kernel<<<(total + 255)/256, 256, 0, stream>>>(
      (const float*)d_in[1],  (const float*)d_in[2],
      (const float*)d_in[3],  (const float*)d_in[4],
      (const float*)d_in[5],  (const float*)d_in[6],
      (const float*)d_in[7],  (const float*)d_in[8],
      (const float*)d_in[9],  (const float*)d_in[10],
      (const float*)d_in[11], (const float*)d_in[12],
      (const float*)d_in[13], (const float*)d_in[14],
      (const float*)d_in[15], (const float*)d_in[16],
      (const float*)d_in[17], (const float*)d_in[18],
      (const float*)d_in[19], (const float*)d_in[20],
      ws);

  lstm_main<<<256, 1024, 0, stream>>>(hist, ws, (float*)d_out);
}